// Round 2
// baseline (783.624 us; speedup 1.0000x reference)
//
#include <hip/hip_runtime.h>

// AttentionMIL: B=8 bags, N=50000 instances, D=256, H=128, C=2
#define B_   8
#define N_   50000
#define D_   256
#define H_   128
#define M_   (B_ * N_)          // 400000 rows
#define EPS_ 1e-5f
#define INV_TAU 3.33333333f     // 1/0.3

#define RB   64                 // rows per block (4 waves x 16 rows each)
#define HSTR 136                // htile row stride in bf16 elems (128+8: 16B-aligned rows, 2-way-max banks)
#define NBLK (M_ / RB)          // 6250 blocks

typedef __attribute__((ext_vector_type(8))) short bf16x8;   // 8 bf16 = 4 VGPRs (MFMA A/B frag)
typedef __attribute__((ext_vector_type(4))) float f32x4;    // MFMA C/D frag

union UB { bf16x8 v; unsigned short u[8]; };
union F8 { float4 f4[2]; float f[8]; };

// fp32 -> bf16 RNE via native cast: compiler emits v_cvt_pk_bf16_f32 pairs
// (m240: scalar-cast path beats hand-written asm; RNE matches the old bit-twiddle).
__device__ __forceinline__ unsigned short f2bf(float f) {
    __bf16 h = (__bf16)f;
    return __builtin_bit_cast(unsigned short, h);
}
__device__ __forceinline__ float bf2f(unsigned short us) {
    return __uint_as_float(((unsigned)us) << 16);
}
__device__ __forceinline__ float fast_tanh(float x) {
    return 1.0f - 2.0f * __fdividef(1.0f, __expf(2.0f * x) + 1.0f);
}

// ---------------------------------------------------------------------------
// k0: repack W1/W2/Wa1 (fp32 [K][128] row-major) into bf16 MFMA-B-frag layout:
//   Wp[((kc*8 + nt)*64 + lane)*8 + j] = bf16(W[kc*32 + (lane>>4)*8 + j][nt*16 + (lane&15)])
// ---------------------------------------------------------------------------
__global__ __launch_bounds__(256)
void k0_pack(const float* __restrict__ W1, const float* __restrict__ W2,
             const float* __restrict__ Wa1,
             unsigned short* __restrict__ W1p, unsigned short* __restrict__ W2p,
             unsigned short* __restrict__ Wa1p)
{
    int t = blockIdx.x * 256 + threadIdx.x;
    const float* src; unsigned short* dst; int idx;
    if (t < 4096)      { src = W1;  dst = W1p;  idx = t; }
    else if (t < 6144) { src = W2;  dst = W2p;  idx = t - 4096; }
    else               { src = Wa1; dst = Wa1p; idx = t - 6144; }
    int l   = idx & 63;
    int nt  = (idx >> 6) & 7;
    int kc  = idx >> 9;
    int col = nt * 16 + (l & 15);
    int kb  = kc * 32 + (l >> 4) * 8;
    UB o;
    #pragma unroll
    for (int j = 0; j < 8; ++j) o.u[j] = f2bf(src[(size_t)(kb + j) * H_ + col]);
    *(bf16x8*)(dst + (size_t)idx * 8) = o.v;
}

// LN(+bias) + ReLU on MFMA C/D-layout accumulators (single 16-row tile),
// store bf16 to htile. C/D layout (16x16x32): col = lane&15, row = (lane>>4)*4 + reg.
__device__ __forceinline__ void ln_relu_store(
    f32x4 (&acc)[8],
    const float* __restrict__ bb, const float* __restrict__ gg, const float* __restrict__ ee,
    unsigned short* __restrict__ htile, int wrow0, int n16, int kq)
{
    float bc[8], gc[8], ec[8];
    #pragma unroll
    for (int nt = 0; nt < 8; ++nt) {
        int col = nt * 16 + n16;
        bc[nt] = bb[col]; gc[nt] = gg[col]; ec[nt] = ee[col];
    }
    #pragma unroll
    for (int r = 0; r < 4; ++r) {
        float v[8];
        float s = 0.f, s2 = 0.f;
        #pragma unroll
        for (int nt = 0; nt < 8; ++nt) {
            float t = acc[nt][r] + bc[nt];
            v[nt] = t; s += t; s2 = fmaf(t, t, s2);
        }
        #pragma unroll
        for (int o = 1; o <= 8; o <<= 1) {
            s  += __shfl_xor(s,  o);
            s2 += __shfl_xor(s2, o);
        }
        float mu  = s * (1.f / H_);
        float var = s2 * (1.f / H_) - mu * mu;
        float rs  = rsqrtf(var + EPS_);
        int row = wrow0 + kq * 4 + r;
        #pragma unroll
        for (int nt = 0; nt < 8; ++nt) {
            float h = fmaxf(fmaf((v[nt] - mu) * rs, gc[nt], ec[nt]), 0.f);
            htile[row * HSTR + nt * 16 + n16] = f2bf(h);
        }
    }
}

// ---------------------------------------------------------------------------
// k1: per 64-row block (4 waves x 16 rows), fully fused:
//   h1 = relu(LN(x@W1+b1)); h2 = relu(LN(h1@W2+b2));
//   w  = exp((tanh(h2@Wa1+ba1)@Wa2 + ba2)/tau)
//   partials per bag slot: Z = sum w, pooled[j] = sum w*h2[:,j]  (h2 from LDS htile)
// Occupancy round: RB 128->64 + single m-tile per wave halves LDS (21.6 KB/block)
// and register pressure (acc 32 AGPR); __launch_bounds__(256,6) -> 6 blocks/CU
// (24 waves/CU, was 16). All per-row math identical to previous version.
// ---------------------------------------------------------------------------
__global__ __launch_bounds__(256, 6)
void k1_mfma(const float* __restrict__ x,
             const unsigned short* __restrict__ W1p,
             const unsigned short* __restrict__ W2p,
             const unsigned short* __restrict__ Wa1p,
             const float* __restrict__ b1, const float* __restrict__ g1, const float* __restrict__ be1,
             const float* __restrict__ b2, const float* __restrict__ g2, const float* __restrict__ be2,
             const float* __restrict__ ba1, const float* __restrict__ Wa2, const float* __restrict__ ba2,
             float* __restrict__ Zarr, float* __restrict__ Pool)
{
    __shared__ __align__(16) unsigned short htile[RB * HSTR];   // 17408 B
    __shared__ float parr[4][2][132];                           // 4224 B

    const int tid   = threadIdx.x;
    const int w     = tid >> 6;
    const int l     = tid & 63;
    const int n16   = l & 15;
    const int kq    = l >> 4;
    const int base  = blockIdx.x * RB;
    const int wrow0 = w * 16;

    f32x4 acc[8];

    // ================= layer 1: x(256) @ W1 -> 128, A prefetched from global =====
    #pragma unroll
    for (int nt = 0; nt < 8; ++nt) acc[nt] = f32x4{0.f, 0.f, 0.f, 0.f};

    const float* xrow0 = x + (size_t)(base + wrow0 + n16) * D_ + kq * 8;
    F8 xb[2];                                     // [buf] (single m-tile)
    xb[0].f4[0] = *(const float4*)xrow0;
    xb[0].f4[1] = *(const float4*)(xrow0 + 4);
    #pragma unroll
    for (int kc = 0; kc < 8; ++kc) {
        const int cur = kc & 1;
        if (kc < 7) {
            const float* xp = xrow0 + (kc + 1) * 32;
            xb[cur ^ 1].f4[0] = *(const float4*)xp;
            xb[cur ^ 1].f4[1] = *(const float4*)(xp + 4);
        }
        UB a;
        #pragma unroll
        for (int jj = 0; jj < 8; ++jj) a.u[jj] = f2bf(xb[cur].f[jj]);
        const bf16x8* bp = (const bf16x8*)W1p + (size_t)kc * 512 + l;
        #pragma unroll
        for (int nt = 0; nt < 8; ++nt) {
            bf16x8 bv = bp[nt * 64];
            acc[nt] = __builtin_amdgcn_mfma_f32_16x16x32_bf16(a.v, bv, acc[nt], 0, 0, 0);
        }
    }
    ln_relu_store(acc, b1, g1, be1, htile, wrow0, n16, kq);

    // ================= layer 2: h1(128) @ W2 -> 128, A from htile ================
    #pragma unroll
    for (int nt = 0; nt < 8; ++nt) acc[nt] = f32x4{0.f, 0.f, 0.f, 0.f};

    #pragma unroll
    for (int kc = 0; kc < 4; ++kc) {
        bf16x8 a = *(const bf16x8*)&htile[(wrow0 + n16) * HSTR + kc * 32 + kq * 8];
        const bf16x8* bp = (const bf16x8*)W2p + (size_t)kc * 512 + l;
        #pragma unroll
        for (int nt = 0; nt < 8; ++nt) {
            bf16x8 bv = bp[nt * 64];
            acc[nt] = __builtin_amdgcn_mfma_f32_16x16x32_bf16(a, bv, acc[nt], 0, 0, 0);
        }
    }
    ln_relu_store(acc, b2, g2, be2, htile, wrow0, n16, kq);  // overwrites h1 (wave-private rows)

    // ================= attention: tanh(h2 @ Wa1 + ba1) . Wa2 + ba2 ===============
    #pragma unroll
    for (int nt = 0; nt < 8; ++nt) acc[nt] = f32x4{0.f, 0.f, 0.f, 0.f};

    #pragma unroll
    for (int kc = 0; kc < 4; ++kc) {
        bf16x8 a = *(const bf16x8*)&htile[(wrow0 + n16) * HSTR + kc * 32 + kq * 8];
        const bf16x8* bp = (const bf16x8*)Wa1p + (size_t)kc * 512 + l;
        #pragma unroll
        for (int nt = 0; nt < 8; ++nt) {
            bf16x8 bv = bp[nt * 64];
            acc[nt] = __builtin_amdgcn_mfma_f32_16x16x32_bf16(a, bv, acc[nt], 0, 0, 0);
        }
    }

    float pmr[4];                                 // score/tau per r row (uniform in 16-lane group)
    {
        float bc[8], wc[8];
        #pragma unroll
        for (int nt = 0; nt < 8; ++nt) {
            int col = nt * 16 + n16;
            bc[nt] = ba1[col]; wc[nt] = Wa2[col];
        }
        const float ba2s = ba2[0];
        #pragma unroll
        for (int r = 0; r < 4; ++r) {
            float p = 0.f;
            #pragma unroll
            for (int nt = 0; nt < 8; ++nt)
                p = fmaf(fast_tanh(acc[nt][r] + bc[nt]), wc[nt], p);
            #pragma unroll
            for (int o = 1; o <= 8; o <<= 1) p += __shfl_xor(p, o);
            pmr[r] = (p + ba2s) * INV_TAU;
        }
    }

    // ================= register pooling: Z + pooled per bag slot =================
    // lane owns cols [n16*8, n16*8+8) of its kq's 4 rows; h2 re-read from htile
    // as aligned ds_read_b128.
    const int bag0 = base / N_;
    int rsplit = (bag0 + 1) * N_ - base;          // rows < rsplit -> slot 0; else slot 1

    float pool[2][8];
    float zz[2] = {0.f, 0.f};
    #pragma unroll
    for (int s = 0; s < 2; ++s)
        #pragma unroll
        for (int jj = 0; jj < 8; ++jj) pool[s][jj] = 0.f;

    const unsigned short* hcol = htile + n16 * 8;

    if (rsplit >= RB) {                           // fast path (block-uniform branch)
        #pragma unroll
        for (int r = 0; r < 4; ++r) {
            float we = __expf(pmr[r]);
            zz[0] += we;
            int row = wrow0 + kq * 4 + r;
            UB hv; hv.v = *(const bf16x8*)&hcol[row * HSTR];
            #pragma unroll
            for (int jj = 0; jj < 8; ++jj)
                pool[0][jj] = fmaf(we, bf2f(hv.u[jj]), pool[0][jj]);
        }
    } else {                                      // straddling block (7 of 6250)
        #pragma unroll
        for (int r = 0; r < 4; ++r) {
            float we = __expf(pmr[r]);
            int row = wrow0 + kq * 4 + r;
            float w0 = (row < rsplit) ? we : 0.f;
            float w1 = we - w0;
            zz[0] += w0; zz[1] += w1;
            UB hv; hv.v = *(const bf16x8*)&hcol[row * HSTR];
            #pragma unroll
            for (int jj = 0; jj < 8; ++jj) {
                float h = bf2f(hv.u[jj]);
                pool[0][jj] = fmaf(w0, h, pool[0][jj]);
                pool[1][jj] = fmaf(w1, h, pool[1][jj]);
            }
        }
    }
    #pragma unroll
    for (int s = 0; s < 2; ++s) {
        zz[s] += __shfl_xor(zz[s], 16);
        zz[s] += __shfl_xor(zz[s], 32);
        #pragma unroll
        for (int jj = 0; jj < 8; ++jj) {
            pool[s][jj] += __shfl_xor(pool[s][jj], 16);
            pool[s][jj] += __shfl_xor(pool[s][jj], 32);
        }
    }
    if (kq == 0) {                                // 16 lanes x 8 cols = 128
        #pragma unroll
        for (int s = 0; s < 2; ++s)
            #pragma unroll
            for (int jj = 0; jj < 8; ++jj)
                parr[w][s][n16 * 8 + jj] = pool[s][jj];
    }
    if (l == 0) {
        parr[w][0][128] = zz[0];
        parr[w][1][128] = zz[1];
    }
    __syncthreads();

    {
        const int slot = tid >> 7, col = tid & 127;
        float s4 = parr[0][slot][col] + parr[1][slot][col]
                 + parr[2][slot][col] + parr[3][slot][col];
        Pool[((size_t)blockIdx.x * 2 + slot) * H_ + col] = s4;
        if (col == 0)
            Zarr[blockIdx.x * 2 + slot] = parr[0][slot][128] + parr[1][slot][128]
                                        + parr[2][slot][128] + parr[3][slot][128];
    }
}

// ---------------------------------------------------------------------------
// k2: per bag, merge block partials (4-way chunked) + both heads. 8 x 512.
// ---------------------------------------------------------------------------
__global__ __launch_bounds__(512)
void k2_combine(const float* __restrict__ Zarr, const float* __restrict__ Pool,
                const float* __restrict__ Wc1, const float* __restrict__ bc1,
                const float* __restrict__ Wc2, const float* __restrict__ bc2,
                const float* __restrict__ Ws1, const float* __restrict__ bs1,
                const float* __restrict__ Ws2, const float* __restrict__ bs2,
                float* __restrict__ out)
{
    const int b   = blockIdx.x;
    const int tid = threadIdx.x;
    const int j   = tid & 127, ch = tid >> 7;
    __shared__ float pacc[4][128];
    __shared__ float zacc[4];
    __shared__ float bl[H_], ul[H_], vl[64];

    const int blk0 = (b * N_) / RB;
    const int blk1 = ((b + 1) * N_ - 1) / RB;
    float ps = 0.f, zs = 0.f;
    for (int blk = blk0 + ch; blk <= blk1; blk += 4) {
        int bag0 = (blk * RB) / N_;
        if (bag0 == b)     { ps += Pool[((size_t)blk * 2 + 0) * H_ + j]; zs += Zarr[blk * 2 + 0]; }
        if (bag0 + 1 == b) { ps += Pool[((size_t)blk * 2 + 1) * H_ + j]; zs += Zarr[blk * 2 + 1]; }
    }
    pacc[ch][j] = ps;
    if (j == 0) zacc[ch] = zs;
    __syncthreads();

    if (tid < 128) {
        float p = pacc[0][j] + pacc[1][j] + pacc[2][j] + pacc[3][j];
        float z = zacc[0] + zacc[1] + zacc[2] + zacc[3];
        bl[j] = p / z;
    }
    __syncthreads();

    if (tid < 128) {
        float a = bc1[j];
        for (int k = 0; k < H_; ++k) a = fmaf(bl[k], Wc1[k * H_ + j], a);
        ul[j] = fmaxf(a, 0.f);
        if (j < 64) {
            float a2 = bs1[j];
            for (int k = 0; k < H_; ++k) a2 = fmaf(bl[k], Ws1[k * 64 + j], a2);
            vl[j] = fmaxf(a2, 0.f);
        }
    }
    __syncthreads();

    if (tid < 2) {
        float a3 = bc2[tid];
        for (int k = 0; k < H_; ++k) a3 = fmaf(ul[k], Wc2[k * 2 + tid], a3);
        out[b * 2 + tid] = a3;
    }
    if (tid == 2) {
        float a4 = bs2[0];
        for (int k = 0; k < 64; ++k) a4 = fmaf(vl[k], Ws2[k], a4);
        out[16 + b] = a4;
    }
}

extern "C" void kernel_launch(void* const* d_in, const int* in_sizes, int n_in,
                              void* d_out, int out_size, void* d_ws, size_t ws_size,
                              hipStream_t stream)
{
    (void)in_sizes; (void)n_in; (void)out_size; (void)ws_size;

    const float* x   = (const float*)d_in[0];
    const float* W1  = (const float*)d_in[1];
    const float* b1  = (const float*)d_in[2];
    const float* g1  = (const float*)d_in[3];
    const float* be1 = (const float*)d_in[4];
    const float* W2  = (const float*)d_in[5];
    const float* b2  = (const float*)d_in[6];
    const float* g2  = (const float*)d_in[7];
    const float* be2 = (const float*)d_in[8];
    const float* Wa1 = (const float*)d_in[9];
    const float* ba1 = (const float*)d_in[10];
    const float* Wa2 = (const float*)d_in[11];
    const float* ba2 = (const float*)d_in[12];
    const float* Wc1 = (const float*)d_in[13];
    const float* bc1 = (const float*)d_in[14];
    const float* Wc2 = (const float*)d_in[15];
    const float* bc2 = (const float*)d_in[16];
    const float* Ws1 = (const float*)d_in[17];
    const float* bs1 = (const float*)d_in[18];
    const float* Ws2 = (const float*)d_in[19];
    const float* bs2 = (const float*)d_in[20];

    // workspace layout (16B-aligned segments)
    char* ws = (char*)d_ws;
    float* Zarr          = (float*)ws;                       // 50,000 B
    float* Pool          = (float*)(ws + 50176);             // 6,400,000 B
    unsigned short* W1p  = (unsigned short*)(ws + 6450176);  // 64 KB
    unsigned short* W2p  = (unsigned short*)(ws + 6515712);  // 32 KB
    unsigned short* Wa1p = (unsigned short*)(ws + 6548480);  // 32 KB

    k0_pack<<<32, 256, 0, stream>>>(W1, W2, Wa1, W1p, W2p, Wa1p);
    k1_mfma<<<NBLK, 256, 0, stream>>>(x, W1p, W2p, Wa1p,
                                      b1, g1, be1, b2, g2, be2,
                                      ba1, Wa2, ba2, Zarr, Pool);
    k2_combine<<<B_, 512, 0, stream>>>(Zarr, Pool, Wc1, bc1, Wc2, bc2,
                                       Ws1, bs1, Ws2, bs2, (float*)d_out);
}

// Round 3
// 691.979 us; speedup vs baseline: 1.1324x; 1.1324x over previous
//
#include <hip/hip_runtime.h>

// AttentionMIL: B=8 bags, N=50000 instances, D=256, H=128, C=2
#define B_   8
#define N_   50000
#define D_   256
#define H_   128
#define M_   (B_ * N_)          // 400000 rows
#define EPS_ 1e-5f
#define INV_TAU 3.33333333f     // 1/0.3

#define RB   128                // rows per block (4 waves x 32 rows: m=2 tiles -> B-load amortized x2)
#define HSTR 136                // htile row stride in bf16 elems (128+8: 16B-aligned rows, 2-way-max banks)
#define NBLK (M_ / RB)          // 3125 blocks

typedef __attribute__((ext_vector_type(8))) short bf16x8;   // 8 bf16 = 4 VGPRs (MFMA A/B frag)
typedef __attribute__((ext_vector_type(4))) float f32x4;    // MFMA C/D frag

union UB { bf16x8 v; unsigned short u[8]; };
union F8 { float4 f4[2]; float f[8]; };

// fp32 -> bf16 RNE via native cast (compiler emits v_cvt_pk_bf16_f32 pairs; m240).
__device__ __forceinline__ unsigned short f2bf(float f) {
    __bf16 h = (__bf16)f;
    return __builtin_bit_cast(unsigned short, h);
}
__device__ __forceinline__ float bf2f(unsigned short us) {
    return __uint_as_float(((unsigned)us) << 16);
}
__device__ __forceinline__ float fast_tanh(float x) {
    return 1.0f - 2.0f * __fdividef(1.0f, __expf(2.0f * x) + 1.0f);
}

// ---------------------------------------------------------------------------
// k0: repack W1/W2/Wa1 (fp32 [K][128] row-major) into bf16 MFMA-B-frag layout:
//   Wp[((kc*8 + nt)*64 + lane)*8 + j] = bf16(W[kc*32 + (lane>>4)*8 + j][nt*16 + (lane&15)])
// ---------------------------------------------------------------------------
__global__ __launch_bounds__(256)
void k0_pack(const float* __restrict__ W1, const float* __restrict__ W2,
             const float* __restrict__ Wa1,
             unsigned short* __restrict__ W1p, unsigned short* __restrict__ W2p,
             unsigned short* __restrict__ Wa1p)
{
    int t = blockIdx.x * 256 + threadIdx.x;
    const float* src; unsigned short* dst; int idx;
    if (t < 4096)      { src = W1;  dst = W1p;  idx = t; }
    else if (t < 6144) { src = W2;  dst = W2p;  idx = t - 4096; }
    else               { src = Wa1; dst = Wa1p; idx = t - 6144; }
    int l   = idx & 63;
    int nt  = (idx >> 6) & 7;
    int kc  = idx >> 9;
    int col = nt * 16 + (l & 15);
    int kb  = kc * 32 + (l >> 4) * 8;
    UB o;
    #pragma unroll
    for (int j = 0; j < 8; ++j) o.u[j] = f2bf(src[(size_t)(kb + j) * H_ + col]);
    *(bf16x8*)(dst + (size_t)idx * 8) = o.v;
}

// LN(+bias) + ReLU on MFMA C/D-layout accumulators, store bf16 to htile.
// C/D layout (16x16x32): col = lane&15, row = (lane>>4)*4 + reg  [m89/m91].
__device__ __forceinline__ void ln_relu_store(
    f32x4 (&acc)[2][8],
    const float* __restrict__ bb, const float* __restrict__ gg, const float* __restrict__ ee,
    unsigned short* __restrict__ htile, int wrow0, int n16, int kq)
{
    float bc[8], gc[8], ec[8];
    #pragma unroll
    for (int nt = 0; nt < 8; ++nt) {
        int col = nt * 16 + n16;
        bc[nt] = bb[col]; gc[nt] = gg[col]; ec[nt] = ee[col];
    }
    #pragma unroll
    for (int m = 0; m < 2; ++m) {
        #pragma unroll
        for (int r = 0; r < 4; ++r) {
            float v[8];
            float s = 0.f, s2 = 0.f;
            #pragma unroll
            for (int nt = 0; nt < 8; ++nt) {
                float t = acc[m][nt][r] + bc[nt];
                v[nt] = t; s += t; s2 = fmaf(t, t, s2);
            }
            #pragma unroll
            for (int o = 1; o <= 8; o <<= 1) {
                s  += __shfl_xor(s,  o);
                s2 += __shfl_xor(s2, o);
            }
            float mu  = s * (1.f / H_);
            float var = s2 * (1.f / H_) - mu * mu;
            float rs  = rsqrtf(var + EPS_);
            int row = wrow0 + m * 16 + kq * 4 + r;
            #pragma unroll
            for (int nt = 0; nt < 8; ++nt) {
                float h = fmaxf(fmaf((v[nt] - mu) * rs, gc[nt], ec[nt]), 0.f);
                htile[row * HSTR + nt * 16 + n16] = f2bf(h);
            }
        }
    }
}

// ---------------------------------------------------------------------------
// k1: per 128-row block (4 waves x 32 rows, m=2 tiles per wave), fully fused:
//   h1 = relu(LN(x@W1+b1)); h2 = relu(LN(h1@W2+b2));
//   w  = exp((tanh(h2@Wa1+ba1)@Wa2 + ba2)/tau)
//   partials per bag slot: Z = sum w, pooled[j] = sum w*h2[:,j]  (h2 from LDS htile)
// m=2 is load-bearing: each B-frag L2 load feeds 2 MFMAs (round-2 RB=64 regression
// showed halving this amortization costs more than the occupancy gain).
// Reg budget ~104 (acc 64 + xb 32 + misc) < 128 cap at 4 blocks/CU -> no spills.
// ---------------------------------------------------------------------------
__global__ __launch_bounds__(256, 4)
void k1_mfma(const float* __restrict__ x,
             const unsigned short* __restrict__ W1p,
             const unsigned short* __restrict__ W2p,
             const unsigned short* __restrict__ Wa1p,
             const float* __restrict__ b1, const float* __restrict__ g1, const float* __restrict__ be1,
             const float* __restrict__ b2, const float* __restrict__ g2, const float* __restrict__ be2,
             const float* __restrict__ ba1, const float* __restrict__ Wa2, const float* __restrict__ ba2,
             float* __restrict__ Zarr, float* __restrict__ Pool)
{
    __shared__ __align__(16) unsigned short htile[RB * HSTR];   // 34816 B
    __shared__ float parr[4][2][132];                           // 4224 B

    const int tid   = threadIdx.x;
    const int w     = tid >> 6;
    const int l     = tid & 63;
    const int n16   = l & 15;
    const int kq    = l >> 4;
    const int base  = blockIdx.x * RB;
    const int wrow0 = w * 32;

    f32x4 acc[2][8];

    // ================= layer 1: x(256) @ W1 -> 128, A prefetched from global =====
    #pragma unroll
    for (int m = 0; m < 2; ++m)
        #pragma unroll
        for (int nt = 0; nt < 8; ++nt) acc[m][nt] = f32x4{0.f, 0.f, 0.f, 0.f};

    const float* xrow0 = x + (size_t)(base + wrow0 + n16) * D_ + kq * 8;
    F8 xb[2][2];                                  // [buf][m]
    #pragma unroll
    for (int m = 0; m < 2; ++m) {
        const float* xp = xrow0 + m * 16 * D_;
        xb[0][m].f4[0] = *(const float4*)xp;
        xb[0][m].f4[1] = *(const float4*)(xp + 4);
    }
    #pragma unroll
    for (int kc = 0; kc < 8; ++kc) {
        const int cur = kc & 1;
        if (kc < 7) {
            #pragma unroll
            for (int m = 0; m < 2; ++m) {
                const float* xp = xrow0 + m * 16 * D_ + (kc + 1) * 32;
                xb[cur ^ 1][m].f4[0] = *(const float4*)xp;
                xb[cur ^ 1][m].f4[1] = *(const float4*)(xp + 4);
            }
        }
        UB a[2];
        #pragma unroll
        for (int m = 0; m < 2; ++m)
            #pragma unroll
            for (int jj = 0; jj < 8; ++jj) a[m].u[jj] = f2bf(xb[cur][m].f[jj]);
        const bf16x8* bp = (const bf16x8*)W1p + (size_t)kc * 512 + l;
        #pragma unroll
        for (int nt = 0; nt < 8; ++nt) {
            bf16x8 bv = bp[nt * 64];
            acc[0][nt] = __builtin_amdgcn_mfma_f32_16x16x32_bf16(a[0].v, bv, acc[0][nt], 0, 0, 0);
            acc[1][nt] = __builtin_amdgcn_mfma_f32_16x16x32_bf16(a[1].v, bv, acc[1][nt], 0, 0, 0);
        }
    }
    ln_relu_store(acc, b1, g1, be1, htile, wrow0, n16, kq);

    // ================= layer 2: h1(128) @ W2 -> 128, A from htile ================
    #pragma unroll
    for (int m = 0; m < 2; ++m)
        #pragma unroll
        for (int nt = 0; nt < 8; ++nt) acc[m][nt] = f32x4{0.f, 0.f, 0.f, 0.f};

    #pragma unroll
    for (int kc = 0; kc < 4; ++kc) {
        bf16x8 a[2];
        #pragma unroll
        for (int m = 0; m < 2; ++m)
            a[m] = *(const bf16x8*)&htile[(wrow0 + m * 16 + n16) * HSTR + kc * 32 + kq * 8];
        const bf16x8* bp = (const bf16x8*)W2p + (size_t)kc * 512 + l;
        #pragma unroll
        for (int nt = 0; nt < 8; ++nt) {
            bf16x8 bv = bp[nt * 64];
            acc[0][nt] = __builtin_amdgcn_mfma_f32_16x16x32_bf16(a[0], bv, acc[0][nt], 0, 0, 0);
            acc[1][nt] = __builtin_amdgcn_mfma_f32_16x16x32_bf16(a[1], bv, acc[1][nt], 0, 0, 0);
        }
    }
    ln_relu_store(acc, b2, g2, be2, htile, wrow0, n16, kq);  // overwrites h1 (wave-private rows)

    // ================= attention: tanh(h2 @ Wa1 + ba1) . Wa2 + ba2 ===============
    #pragma unroll
    for (int m = 0; m < 2; ++m)
        #pragma unroll
        for (int nt = 0; nt < 8; ++nt) acc[m][nt] = f32x4{0.f, 0.f, 0.f, 0.f};

    #pragma unroll
    for (int kc = 0; kc < 4; ++kc) {
        bf16x8 a[2];
        #pragma unroll
        for (int m = 0; m < 2; ++m)
            a[m] = *(const bf16x8*)&htile[(wrow0 + m * 16 + n16) * HSTR + kc * 32 + kq * 8];
        const bf16x8* bp = (const bf16x8*)Wa1p + (size_t)kc * 512 + l;
        #pragma unroll
        for (int nt = 0; nt < 8; ++nt) {
            bf16x8 bv = bp[nt * 64];
            acc[0][nt] = __builtin_amdgcn_mfma_f32_16x16x32_bf16(a[0], bv, acc[0][nt], 0, 0, 0);
            acc[1][nt] = __builtin_amdgcn_mfma_f32_16x16x32_bf16(a[1], bv, acc[1][nt], 0, 0, 0);
        }
    }

    float pmr[2][4];                              // score/tau per (m,r) row (uniform in 16-lane group)
    {
        float bc[8], wc[8];
        #pragma unroll
        for (int nt = 0; nt < 8; ++nt) {
            int col = nt * 16 + n16;
            bc[nt] = ba1[col]; wc[nt] = Wa2[col];
        }
        const float ba2s = ba2[0];
        #pragma unroll
        for (int m = 0; m < 2; ++m) {
            #pragma unroll
            for (int r = 0; r < 4; ++r) {
                float p = 0.f;
                #pragma unroll
                for (int nt = 0; nt < 8; ++nt)
                    p = fmaf(fast_tanh(acc[m][nt][r] + bc[nt]), wc[nt], p);
                #pragma unroll
                for (int o = 1; o <= 8; o <<= 1) p += __shfl_xor(p, o);
                pmr[m][r] = (p + ba2s) * INV_TAU;
            }
        }
    }

    // ================= register pooling: Z + pooled per bag slot =================
    // lane owns cols [n16*8, n16*8+8) of its kq's 8 rows; h2 re-read from htile
    // as aligned ds_read_b128 (conflict-free; no h2p register cache -> no spills).
    const int bag0 = base / N_;
    int rsplit = (bag0 + 1) * N_ - base;          // rows < rsplit -> slot 0; else slot 1

    float pool[2][8];
    float zz[2] = {0.f, 0.f};
    #pragma unroll
    for (int s = 0; s < 2; ++s)
        #pragma unroll
        for (int jj = 0; jj < 8; ++jj) pool[s][jj] = 0.f;

    const unsigned short* hcol = htile + n16 * 8;

    if (rsplit >= RB) {                           // fast path (block-uniform branch)
        #pragma unroll
        for (int m = 0; m < 2; ++m)
            #pragma unroll
            for (int r = 0; r < 4; ++r) {
                float we = __expf(pmr[m][r]);
                zz[0] += we;
                int row = wrow0 + m * 16 + kq * 4 + r;
                UB hv; hv.v = *(const bf16x8*)&hcol[row * HSTR];
                #pragma unroll
                for (int jj = 0; jj < 8; ++jj)
                    pool[0][jj] = fmaf(we, bf2f(hv.u[jj]), pool[0][jj]);
            }
    } else {                                      // straddling block (7 of 3125)
        #pragma unroll
        for (int m = 0; m < 2; ++m)
            #pragma unroll
            for (int r = 0; r < 4; ++r) {
                float we = __expf(pmr[m][r]);
                int row = wrow0 + m * 16 + kq * 4 + r;
                float w0 = (row < rsplit) ? we : 0.f;
                float w1 = we - w0;
                zz[0] += w0; zz[1] += w1;
                UB hv; hv.v = *(const bf16x8*)&hcol[row * HSTR];
                #pragma unroll
                for (int jj = 0; jj < 8; ++jj) {
                    float h = bf2f(hv.u[jj]);
                    pool[0][jj] = fmaf(w0, h, pool[0][jj]);
                    pool[1][jj] = fmaf(w1, h, pool[1][jj]);
                }
            }
    }
    #pragma unroll
    for (int s = 0; s < 2; ++s) {
        zz[s] += __shfl_xor(zz[s], 16);
        zz[s] += __shfl_xor(zz[s], 32);
        #pragma unroll
        for (int jj = 0; jj < 8; ++jj) {
            pool[s][jj] += __shfl_xor(pool[s][jj], 16);
            pool[s][jj] += __shfl_xor(pool[s][jj], 32);
        }
    }
    if (kq == 0) {                                // 16 lanes x 8 cols = 128
        #pragma unroll
        for (int s = 0; s < 2; ++s)
            #pragma unroll
            for (int jj = 0; jj < 8; ++jj)
                parr[w][s][n16 * 8 + jj] = pool[s][jj];
    }
    if (l == 0) {
        parr[w][0][128] = zz[0];
        parr[w][1][128] = zz[1];
    }
    __syncthreads();

    {
        const int slot = tid >> 7, col = tid & 127;
        float s4 = parr[0][slot][col] + parr[1][slot][col]
                 + parr[2][slot][col] + parr[3][slot][col];
        Pool[((size_t)blockIdx.x * 2 + slot) * H_ + col] = s4;
        if (col == 0)
            Zarr[blockIdx.x * 2 + slot] = parr[0][slot][128] + parr[1][slot][128]
                                        + parr[2][slot][128] + parr[3][slot][128];
    }
}

// ---------------------------------------------------------------------------
// k2: per bag, merge block partials (8-way chunked, 1024 threads) + both heads.
// Round-2 evidence: the merge loop is latency-bound and scales with NBLK;
// 8 chunks + unroll-4 gives ~8x more loads in flight vs the old 4x512 version.
// ---------------------------------------------------------------------------
__global__ __launch_bounds__(1024)
void k2_combine(const float* __restrict__ Zarr, const float* __restrict__ Pool,
                const float* __restrict__ Wc1, const float* __restrict__ bc1,
                const float* __restrict__ Wc2, const float* __restrict__ bc2,
                const float* __restrict__ Ws1, const float* __restrict__ bs1,
                const float* __restrict__ Ws2, const float* __restrict__ bs2,
                float* __restrict__ out)
{
    const int b   = blockIdx.x;
    const int tid = threadIdx.x;
    const int j   = tid & 127, ch = tid >> 7;     // 8 chunks of 128 cols
    __shared__ float pacc[8][128];
    __shared__ float zacc[8];
    __shared__ float bl[H_], ul[H_], vl[64];

    const int blk0 = (b * N_) / RB;
    const int blk1 = ((b + 1) * N_ - 1) / RB;
    float ps = 0.f, zs = 0.f;
    #pragma unroll 4
    for (int blk = blk0 + ch; blk <= blk1; blk += 8) {
        int bag0 = (blk * RB) / N_;
        if (bag0 == b)     { ps += Pool[((size_t)blk * 2 + 0) * H_ + j]; zs += Zarr[blk * 2 + 0]; }
        if (bag0 + 1 == b) { ps += Pool[((size_t)blk * 2 + 1) * H_ + j]; zs += Zarr[blk * 2 + 1]; }
    }
    pacc[ch][j] = ps;
    if (j == 0) zacc[ch] = zs;
    __syncthreads();

    if (tid < 128) {
        float p = 0.f, z = 0.f;
        #pragma unroll
        for (int c = 0; c < 8; ++c) { p += pacc[c][j]; z += zacc[c]; }
        bl[j] = p / z;
    }
    __syncthreads();

    if (tid < 128) {
        float a = bc1[j];
        for (int k = 0; k < H_; ++k) a = fmaf(bl[k], Wc1[k * H_ + j], a);
        ul[j] = fmaxf(a, 0.f);
        if (j < 64) {
            float a2 = bs1[j];
            for (int k = 0; k < H_; ++k) a2 = fmaf(bl[k], Ws1[k * 64 + j], a2);
            vl[j] = fmaxf(a2, 0.f);
        }
    }
    __syncthreads();

    if (tid < 2) {
        float a3 = bc2[tid];
        for (int k = 0; k < H_; ++k) a3 = fmaf(ul[k], Wc2[k * 2 + tid], a3);
        out[b * 2 + tid] = a3;
    }
    if (tid == 2) {
        float a4 = bs2[0];
        for (int k = 0; k < 64; ++k) a4 = fmaf(vl[k], Ws2[k], a4);
        out[16 + b] = a4;
    }
}

extern "C" void kernel_launch(void* const* d_in, const int* in_sizes, int n_in,
                              void* d_out, int out_size, void* d_ws, size_t ws_size,
                              hipStream_t stream)
{
    (void)in_sizes; (void)n_in; (void)out_size; (void)ws_size;

    const float* x   = (const float*)d_in[0];
    const float* W1  = (const float*)d_in[1];
    const float* b1  = (const float*)d_in[2];
    const float* g1  = (const float*)d_in[3];
    const float* be1 = (const float*)d_in[4];
    const float* W2  = (const float*)d_in[5];
    const float* b2  = (const float*)d_in[6];
    const float* g2  = (const float*)d_in[7];
    const float* be2 = (const float*)d_in[8];
    const float* Wa1 = (const float*)d_in[9];
    const float* ba1 = (const float*)d_in[10];
    const float* Wa2 = (const float*)d_in[11];
    const float* ba2 = (const float*)d_in[12];
    const float* Wc1 = (const float*)d_in[13];
    const float* bc1 = (const float*)d_in[14];
    const float* Wc2 = (const float*)d_in[15];
    const float* bc2 = (const float*)d_in[16];
    const float* Ws1 = (const float*)d_in[17];
    const float* bs1 = (const float*)d_in[18];
    const float* Ws2 = (const float*)d_in[19];
    const float* bs2 = (const float*)d_in[20];

    // workspace layout (16B-aligned segments)
    char* ws = (char*)d_ws;
    float* Zarr          = (float*)ws;                       // 25,000 B
    float* Pool          = (float*)(ws + 25088);             // 3,200,000 B
    unsigned short* W1p  = (unsigned short*)(ws + 3225088);  // 64 KB
    unsigned short* W2p  = (unsigned short*)(ws + 3290624);  // 32 KB
    unsigned short* Wa1p = (unsigned short*)(ws + 3323392);  // 32 KB

    k0_pack<<<32, 256, 0, stream>>>(W1, W2, Wa1, W1p, W2p, Wa1p);
    k1_mfma<<<NBLK, 256, 0, stream>>>(x, W1p, W2p, Wa1p,
                                      b1, g1, be1, b2, g2, be2,
                                      ba1, Wa2, ba2, Zarr, Pool);
    k2_combine<<<B_, 1024, 0, stream>>>(Zarr, Pool, Wc1, bc1, Wc2, bc2,
                                        Ws1, bs1, Ws2, bs2, (float*)d_out);
}

// Round 4
// 680.592 us; speedup vs baseline: 1.1514x; 1.0167x over previous
//
#include <hip/hip_runtime.h>

// AttentionMIL: B=8 bags, N=50000 instances, D=256, H=128, C=2
#define B_   8
#define N_   50000
#define D_   256
#define H_   128
#define M_   (B_ * N_)          // 400000 rows
#define EPS_ 1e-5f
#define INV_TAU 3.33333333f     // 1/0.3

#define RB   128                // rows per block (4 waves x 32 rows: m=2 tiles -> B-load amortized x2)
#define HSTR 136                // htile row stride in bf16 elems (128+8: 16B-aligned rows, 2-way-max banks)
#define NBLK (M_ / RB)          // 3125 blocks

typedef __attribute__((ext_vector_type(8))) short bf16x8;   // 8 bf16 = 4 VGPRs (MFMA A/B frag)
typedef __attribute__((ext_vector_type(4))) float f32x4;    // MFMA C/D frag

union UB { bf16x8 v; unsigned short u[8]; };
union F8 { float4 f4[2]; float f[8]; };

// fp32 -> bf16 RNE via native cast (compiler emits v_cvt_pk_bf16_f32 pairs; m240).
__device__ __forceinline__ unsigned short f2bf(float f) {
    __bf16 h = (__bf16)f;
    return __builtin_bit_cast(unsigned short, h);
}
__device__ __forceinline__ float bf2f(unsigned short us) {
    return __uint_as_float(((unsigned)us) << 16);
}
__device__ __forceinline__ float fast_tanh(float x) {
    return 1.0f - 2.0f * __fdividef(1.0f, __expf(2.0f * x) + 1.0f);
}

// ---------------------------------------------------------------------------
// k0: repack W1/W2/Wa1 (fp32 [K][128] row-major) into bf16 MFMA-B-frag layout:
//   Wp[((kc*8 + nt)*64 + lane)*8 + j] = bf16(W[kc*32 + (lane>>4)*8 + j][nt*16 + (lane&15)])
// ---------------------------------------------------------------------------
__global__ __launch_bounds__(256)
void k0_pack(const float* __restrict__ W1, const float* __restrict__ W2,
             const float* __restrict__ Wa1,
             unsigned short* __restrict__ W1p, unsigned short* __restrict__ W2p,
             unsigned short* __restrict__ Wa1p)
{
    int t = blockIdx.x * 256 + threadIdx.x;
    const float* src; unsigned short* dst; int idx;
    if (t < 4096)      { src = W1;  dst = W1p;  idx = t; }
    else if (t < 6144) { src = W2;  dst = W2p;  idx = t - 4096; }
    else               { src = Wa1; dst = Wa1p; idx = t - 6144; }
    int l   = idx & 63;
    int nt  = (idx >> 6) & 7;
    int kc  = idx >> 9;
    int col = nt * 16 + (l & 15);
    int kb  = kc * 32 + (l >> 4) * 8;
    UB o;
    #pragma unroll
    for (int j = 0; j < 8; ++j) o.u[j] = f2bf(src[(size_t)(kb + j) * H_ + col]);
    *(bf16x8*)(dst + (size_t)idx * 8) = o.v;
}

// LN(+bias) + ReLU on MFMA C/D-layout accumulators, store bf16 to htile.
// C/D layout (16x16x32): col = lane&15, row = (lane>>4)*4 + reg  [m89/m91].
__device__ __forceinline__ void ln_relu_store(
    f32x4 (&acc)[2][8],
    const float* __restrict__ bb, const float* __restrict__ gg, const float* __restrict__ ee,
    unsigned short* __restrict__ htile, int wrow0, int n16, int kq)
{
    float bc[8], gc[8], ec[8];
    #pragma unroll
    for (int nt = 0; nt < 8; ++nt) {
        int col = nt * 16 + n16;
        bc[nt] = bb[col]; gc[nt] = gg[col]; ec[nt] = ee[col];
    }
    #pragma unroll
    for (int m = 0; m < 2; ++m) {
        #pragma unroll
        for (int r = 0; r < 4; ++r) {
            float v[8];
            float s = 0.f, s2 = 0.f;
            #pragma unroll
            for (int nt = 0; nt < 8; ++nt) {
                float t = acc[m][nt][r] + bc[nt];
                v[nt] = t; s += t; s2 = fmaf(t, t, s2);
            }
            #pragma unroll
            for (int o = 1; o <= 8; o <<= 1) {
                s  += __shfl_xor(s,  o);
                s2 += __shfl_xor(s2, o);
            }
            float mu  = s * (1.f / H_);
            float var = s2 * (1.f / H_) - mu * mu;
            float rs  = rsqrtf(var + EPS_);
            int row = wrow0 + m * 16 + kq * 4 + r;
            #pragma unroll
            for (int nt = 0; nt < 8; ++nt) {
                float h = fmaxf(fmaf((v[nt] - mu) * rs, gc[nt], ec[nt]), 0.f);
                htile[row * HSTR + nt * 16 + n16] = f2bf(h);
            }
        }
    }
}

// ---------------------------------------------------------------------------
// k1: per 128-row block (4 waves x 32 rows, m=2 tiles per wave), fully fused:
//   h1 = relu(LN(x@W1+b1)); h2 = relu(LN(h1@W2+b2));
//   w  = exp((tanh(h2@Wa1+ba1)@Wa2 + ba2)/tau)
//   per-bag partials: Z = sum w, pooled[j] = sum w*h2[:,j]
// This round: block partials go straight into PoolAcc[8][128]/Zacc[8] via
// atomicAdd (contention ~391/address, hidden under other blocks' compute) —
// eliminates the 3.2 MB Pool spill + k2's 8-CU latency-bound merge (~60 us).
// m=2 is load-bearing (round-2 RB=64 regression). Reg budget <128 -> no spills.
// ---------------------------------------------------------------------------
__global__ __launch_bounds__(256, 4)
void k1_mfma(const float* __restrict__ x,
             const unsigned short* __restrict__ W1p,
             const unsigned short* __restrict__ W2p,
             const unsigned short* __restrict__ Wa1p,
             const float* __restrict__ b1, const float* __restrict__ g1, const float* __restrict__ be1,
             const float* __restrict__ b2, const float* __restrict__ g2, const float* __restrict__ be2,
             const float* __restrict__ ba1, const float* __restrict__ Wa2, const float* __restrict__ ba2,
             float* __restrict__ Zacc, float* __restrict__ PoolAcc)
{
    __shared__ __align__(16) unsigned short htile[RB * HSTR];   // 34816 B
    __shared__ float parr[4][2][132];                           // 4224 B

    const int tid   = threadIdx.x;
    const int w     = tid >> 6;
    const int l     = tid & 63;
    const int n16   = l & 15;
    const int kq    = l >> 4;
    const int base  = blockIdx.x * RB;
    const int wrow0 = w * 32;

    f32x4 acc[2][8];

    // ================= layer 1: x(256) @ W1 -> 128, A prefetched from global =====
    #pragma unroll
    for (int m = 0; m < 2; ++m)
        #pragma unroll
        for (int nt = 0; nt < 8; ++nt) acc[m][nt] = f32x4{0.f, 0.f, 0.f, 0.f};

    const float* xrow0 = x + (size_t)(base + wrow0 + n16) * D_ + kq * 8;
    F8 xb[2][2];                                  // [buf][m]
    #pragma unroll
    for (int m = 0; m < 2; ++m) {
        const float* xp = xrow0 + m * 16 * D_;
        xb[0][m].f4[0] = *(const float4*)xp;
        xb[0][m].f4[1] = *(const float4*)(xp + 4);
    }
    #pragma unroll
    for (int kc = 0; kc < 8; ++kc) {
        const int cur = kc & 1;
        if (kc < 7) {
            #pragma unroll
            for (int m = 0; m < 2; ++m) {
                const float* xp = xrow0 + m * 16 * D_ + (kc + 1) * 32;
                xb[cur ^ 1][m].f4[0] = *(const float4*)xp;
                xb[cur ^ 1][m].f4[1] = *(const float4*)(xp + 4);
            }
        }
        UB a[2];
        #pragma unroll
        for (int m = 0; m < 2; ++m)
            #pragma unroll
            for (int jj = 0; jj < 8; ++jj) a[m].u[jj] = f2bf(xb[cur][m].f[jj]);
        const bf16x8* bp = (const bf16x8*)W1p + (size_t)kc * 512 + l;
        #pragma unroll
        for (int nt = 0; nt < 8; ++nt) {
            bf16x8 bv = bp[nt * 64];
            acc[0][nt] = __builtin_amdgcn_mfma_f32_16x16x32_bf16(a[0].v, bv, acc[0][nt], 0, 0, 0);
            acc[1][nt] = __builtin_amdgcn_mfma_f32_16x16x32_bf16(a[1].v, bv, acc[1][nt], 0, 0, 0);
        }
    }
    ln_relu_store(acc, b1, g1, be1, htile, wrow0, n16, kq);

    // ================= layer 2: h1(128) @ W2 -> 128, A from htile ================
    #pragma unroll
    for (int m = 0; m < 2; ++m)
        #pragma unroll
        for (int nt = 0; nt < 8; ++nt) acc[m][nt] = f32x4{0.f, 0.f, 0.f, 0.f};

    #pragma unroll
    for (int kc = 0; kc < 4; ++kc) {
        bf16x8 a[2];
        #pragma unroll
        for (int m = 0; m < 2; ++m)
            a[m] = *(const bf16x8*)&htile[(wrow0 + m * 16 + n16) * HSTR + kc * 32 + kq * 8];
        const bf16x8* bp = (const bf16x8*)W2p + (size_t)kc * 512 + l;
        #pragma unroll
        for (int nt = 0; nt < 8; ++nt) {
            bf16x8 bv = bp[nt * 64];
            acc[0][nt] = __builtin_amdgcn_mfma_f32_16x16x32_bf16(a[0], bv, acc[0][nt], 0, 0, 0);
            acc[1][nt] = __builtin_amdgcn_mfma_f32_16x16x32_bf16(a[1], bv, acc[1][nt], 0, 0, 0);
        }
    }
    ln_relu_store(acc, b2, g2, be2, htile, wrow0, n16, kq);  // overwrites h1 (wave-private rows)

    // ================= attention: tanh(h2 @ Wa1 + ba1) . Wa2 + ba2 ===============
    #pragma unroll
    for (int m = 0; m < 2; ++m)
        #pragma unroll
        for (int nt = 0; nt < 8; ++nt) acc[m][nt] = f32x4{0.f, 0.f, 0.f, 0.f};

    #pragma unroll
    for (int kc = 0; kc < 4; ++kc) {
        bf16x8 a[2];
        #pragma unroll
        for (int m = 0; m < 2; ++m)
            a[m] = *(const bf16x8*)&htile[(wrow0 + m * 16 + n16) * HSTR + kc * 32 + kq * 8];
        const bf16x8* bp = (const bf16x8*)Wa1p + (size_t)kc * 512 + l;
        #pragma unroll
        for (int nt = 0; nt < 8; ++nt) {
            bf16x8 bv = bp[nt * 64];
            acc[0][nt] = __builtin_amdgcn_mfma_f32_16x16x32_bf16(a[0], bv, acc[0][nt], 0, 0, 0);
            acc[1][nt] = __builtin_amdgcn_mfma_f32_16x16x32_bf16(a[1], bv, acc[1][nt], 0, 0, 0);
        }
    }

    float pmr[2][4];                              // score/tau per (m,r) row (uniform in 16-lane group)
    {
        float bc[8], wc[8];
        #pragma unroll
        for (int nt = 0; nt < 8; ++nt) {
            int col = nt * 16 + n16;
            bc[nt] = ba1[col]; wc[nt] = Wa2[col];
        }
        const float ba2s = ba2[0];
        #pragma unroll
        for (int m = 0; m < 2; ++m) {
            #pragma unroll
            for (int r = 0; r < 4; ++r) {
                float p = 0.f;
                #pragma unroll
                for (int nt = 0; nt < 8; ++nt)
                    p = fmaf(fast_tanh(acc[m][nt][r] + bc[nt]), wc[nt], p);
                #pragma unroll
                for (int o = 1; o <= 8; o <<= 1) p += __shfl_xor(p, o);
                pmr[m][r] = (p + ba2s) * INV_TAU;
            }
        }
    }

    // ================= register pooling: Z + pooled per bag slot =================
    // lane owns cols [n16*8, n16*8+8) of its kq's 8 rows; h2 re-read from htile
    // as aligned ds_read_b128 (conflict-free; no h2p register cache -> no spills).
    const int bag0 = base / N_;
    int rsplit = (bag0 + 1) * N_ - base;          // rows < rsplit -> slot 0; else slot 1

    float pool[2][8];
    float zz[2] = {0.f, 0.f};
    #pragma unroll
    for (int s = 0; s < 2; ++s)
        #pragma unroll
        for (int jj = 0; jj < 8; ++jj) pool[s][jj] = 0.f;

    const unsigned short* hcol = htile + n16 * 8;

    if (rsplit >= RB) {                           // fast path (block-uniform branch)
        #pragma unroll
        for (int m = 0; m < 2; ++m)
            #pragma unroll
            for (int r = 0; r < 4; ++r) {
                float we = __expf(pmr[m][r]);
                zz[0] += we;
                int row = wrow0 + m * 16 + kq * 4 + r;
                UB hv; hv.v = *(const bf16x8*)&hcol[row * HSTR];
                #pragma unroll
                for (int jj = 0; jj < 8; ++jj)
                    pool[0][jj] = fmaf(we, bf2f(hv.u[jj]), pool[0][jj]);
            }
    } else {                                      // straddling block (7 of 3125)
        #pragma unroll
        for (int m = 0; m < 2; ++m)
            #pragma unroll
            for (int r = 0; r < 4; ++r) {
                float we = __expf(pmr[m][r]);
                int row = wrow0 + m * 16 + kq * 4 + r;
                float w0 = (row < rsplit) ? we : 0.f;
                float w1 = we - w0;
                zz[0] += w0; zz[1] += w1;
                UB hv; hv.v = *(const bf16x8*)&hcol[row * HSTR];
                #pragma unroll
                for (int jj = 0; jj < 8; ++jj) {
                    float h = bf2f(hv.u[jj]);
                    pool[0][jj] = fmaf(w0, h, pool[0][jj]);
                    pool[1][jj] = fmaf(w1, h, pool[1][jj]);
                }
            }
    }
    #pragma unroll
    for (int s = 0; s < 2; ++s) {
        zz[s] += __shfl_xor(zz[s], 16);
        zz[s] += __shfl_xor(zz[s], 32);
        #pragma unroll
        for (int jj = 0; jj < 8; ++jj) {
            pool[s][jj] += __shfl_xor(pool[s][jj], 16);
            pool[s][jj] += __shfl_xor(pool[s][jj], 32);
        }
    }
    if (kq == 0) {                                // 16 lanes x 8 cols = 128
        #pragma unroll
        for (int s = 0; s < 2; ++s)
            #pragma unroll
            for (int jj = 0; jj < 8; ++jj)
                parr[w][s][n16 * 8 + jj] = pool[s][jj];
    }
    if (l == 0) {
        parr[w][0][128] = zz[0];
        parr[w][1][128] = zz[1];
    }
    __syncthreads();

    {
        const int slot = tid >> 7, col = tid & 127;
        if (slot == 0 || rsplit < RB) {           // slot 1 only exists for straddlers
            float s4 = parr[0][slot][col] + parr[1][slot][col]
                     + parr[2][slot][col] + parr[3][slot][col];
            const int bag = bag0 + slot;
            atomicAdd(&PoolAcc[(size_t)bag * H_ + col], s4);
            if (col == 0) {
                float z4 = parr[0][slot][128] + parr[1][slot][128]
                         + parr[2][slot][128] + parr[3][slot][128];
                atomicAdd(&Zacc[bag], z4);
            }
        }
    }
}

// ---------------------------------------------------------------------------
// k2: per bag, heads only (merge already done by k1's atomics). 8 x 128.
// ---------------------------------------------------------------------------
__global__ __launch_bounds__(128)
void k2_heads(const float* __restrict__ Zacc, const float* __restrict__ PoolAcc,
              const float* __restrict__ Wc1, const float* __restrict__ bc1,
              const float* __restrict__ Wc2, const float* __restrict__ bc2,
              const float* __restrict__ Ws1, const float* __restrict__ bs1,
              const float* __restrict__ Ws2, const float* __restrict__ bs2,
              float* __restrict__ out)
{
    const int b = blockIdx.x;
    const int j = threadIdx.x;                    // 0..127
    __shared__ float bl[H_], ul[H_], vl[64];

    bl[j] = PoolAcc[(size_t)b * H_ + j] / Zacc[b];
    __syncthreads();

    {
        float a = bc1[j];
        for (int k = 0; k < H_; ++k) a = fmaf(bl[k], Wc1[k * H_ + j], a);
        ul[j] = fmaxf(a, 0.f);
        if (j < 64) {
            float a2 = bs1[j];
            for (int k = 0; k < H_; ++k) a2 = fmaf(bl[k], Ws1[k * 64 + j], a2);
            vl[j] = fmaxf(a2, 0.f);
        }
    }
    __syncthreads();

    if (j < 2) {
        float a3 = bc2[j];
        for (int k = 0; k < H_; ++k) a3 = fmaf(ul[k], Wc2[k * 2 + j], a3);
        out[b * 2 + j] = a3;
    }
    if (j == 2) {
        float a4 = bs2[0];
        for (int k = 0; k < 64; ++k) a4 = fmaf(vl[k], Ws2[k], a4);
        out[16 + b] = a4;
    }
}

extern "C" void kernel_launch(void* const* d_in, const int* in_sizes, int n_in,
                              void* d_out, int out_size, void* d_ws, size_t ws_size,
                              hipStream_t stream)
{
    (void)in_sizes; (void)n_in; (void)out_size; (void)ws_size;

    const float* x   = (const float*)d_in[0];
    const float* W1  = (const float*)d_in[1];
    const float* b1  = (const float*)d_in[2];
    const float* g1  = (const float*)d_in[3];
    const float* be1 = (const float*)d_in[4];
    const float* W2  = (const float*)d_in[5];
    const float* b2  = (const float*)d_in[6];
    const float* g2  = (const float*)d_in[7];
    const float* be2 = (const float*)d_in[8];
    const float* Wa1 = (const float*)d_in[9];
    const float* ba1 = (const float*)d_in[10];
    const float* Wa2 = (const float*)d_in[11];
    const float* ba2 = (const float*)d_in[12];
    const float* Wc1 = (const float*)d_in[13];
    const float* bc1 = (const float*)d_in[14];
    const float* Wc2 = (const float*)d_in[15];
    const float* bc2 = (const float*)d_in[16];
    const float* Ws1 = (const float*)d_in[17];
    const float* bs1 = (const float*)d_in[18];
    const float* Ws2 = (const float*)d_in[19];
    const float* bs2 = (const float*)d_in[20];

    // workspace layout (16B-aligned segments)
    char* ws = (char*)d_ws;
    float* Zacc          = (float*)ws;                       // 32 B (8 floats)
    float* PoolAcc       = (float*)(ws + 128);               // 4096 B (8 x 128)
    unsigned short* W1p  = (unsigned short*)(ws + 4352);     // 64 KB
    unsigned short* W2p  = (unsigned short*)(ws + 69888);    // 32 KB
    unsigned short* Wa1p = (unsigned short*)(ws + 102656);   // 32 KB

    hipMemsetAsync(ws, 0, 4352, stream);          // zero Zacc + PoolAcc (graph-safe)
    k0_pack<<<32, 256, 0, stream>>>(W1, W2, Wa1, W1p, W2p, Wa1p);
    k1_mfma<<<NBLK, 256, 0, stream>>>(x, W1p, W2p, Wa1p,
                                      b1, g1, be1, b2, g2, be2,
                                      ba1, Wa2, ba2, Zacc, PoolAcc);
    k2_heads<<<B_, 128, 0, stream>>>(Zacc, PoolAcc, Wc1, bc1, Wc2, bc2,
                                     Ws1, bs1, Ws2, bs2, (float*)d_out);
}